// Round 7
// baseline (95.744 us; speedup 1.0000x reference)
//
#include <hip/hip_runtime.h>
#include <hip/hip_bf16.h>
#include <stdint.h>

#define GAMMA 1e-4f

typedef int i32x4 __attribute__((ext_vector_type(4)));
typedef int i32x8 __attribute__((ext_vector_type(8)));
typedef float f32x4 __attribute__((ext_vector_type(4)));

__device__ __forceinline__ float bf2f(unsigned short u) {
  unsigned int x = ((unsigned int)u) << 16;
  float f; __builtin_memcpy(&f, &x, 4);
  return f;
}

// bit-exact float -> OCP e4m3fn (RNE, satfinite).
__device__ __forceinline__ unsigned char f2e4m3(float x) {
  float a = fabsf(x);
  unsigned char s = x < 0.f ? 0x80 : 0;
  a = fminf(a, 448.f);
  if (a < 0.015625f) {                    // subnormal region, ulp 2^-9
    int q = (int)rintf(a * 512.f);
    return s | (unsigned char)q;
  }
  unsigned int u; __builtin_memcpy(&u, &a, 4);
  u += 0x7FFFFu + ((u >> 20) & 1);        // RNE to 3 mantissa bits
  u &= 0xFFF00000u;
  int e2 = (int)(u >> 23) - 127;
  unsigned int mant = (u >> 20) & 7;
  return s | (unsigned char)(((e2 + 7) << 3) | mant);
}

__device__ __forceinline__ unsigned int pack4(float a, float b, float c, float d) {
  return (unsigned)f2e4m3(a) | ((unsigned)f2e4m3(b) << 8) |
         ((unsigned)f2e4m3(c) << 16) | ((unsigned)f2e4m3(d) << 24);
}

// ---------------- Kernel 1: merged prep (fp8 outputs, fp32 norms) ----------------
__global__ __launch_bounds__(256) void prep_k(
    const float* __restrict__ x, const float* __restrict__ cw,
    const float* __restrict__ cb, unsigned char* __restrict__ fA8,
    float* __restrict__ f2, const float* __restrict__ pr,
    unsigned char* __restrict__ pB8, float* __restrict__ p2) {
  const int tid = threadIdx.x;
  __shared__ float red[4];
  if (blockIdx.x < 4096) {
    const int j = blockIdx.x;
    const float4* src = (const float4*)(pr + (size_t)j * 4096);
    float ssq = 0.f;
    unsigned int w4[4];
#pragma unroll
    for (int k = 0; k < 4; k++) {
      float4 v = src[tid * 4 + k];
      ssq += v.x * v.x + v.y * v.y + v.z * v.z + v.w * v.w;
      w4[k] = pack4(v.x, v.y, v.z, v.w);
    }
    *(uint4*)(pB8 + (size_t)j * 4096 + tid * 16) = make_uint4(w4[0], w4[1], w4[2], w4[3]);
    for (int off = 32; off > 0; off >>= 1) ssq += __shfl_down(ssq, off);
    if ((tid & 63) == 0) red[tid >> 6] = ssq;
    __syncthreads();
    if (tid == 0) p2[j] = red[0] + red[1] + red[2] + red[3];
  } else {
    const int b = blockIdx.x - 4096;
    __shared__ float swb[20];
    if (tid < 16) swb[tid] = cw[tid];
    else if (tid < 20) swb[tid] = cb[tid - 16];
    __syncthreads();
    float w[16], bias[4];
#pragma unroll
    for (int i = 0; i < 16; i++) w[i] = swb[i];
#pragma unroll
    for (int c = 0; c < 4; c++) bias[c] = swb[16 + c];
    const float* xb = x + (size_t)b * 4096;
    unsigned char* fb8 = fA8 + (size_t)b * 4096;
    const int p0 = tid * 4;
    const int h = p0 >> 5, w0 = p0 & 31;
    const float* r0 = xb + (2 * h) * 64 + 2 * w0;
    const float* r1 = r0 + 64;
    float4 a0 = *(const float4*)r0, a1 = *(const float4*)(r0 + 4);
    float4 c0 = *(const float4*)r1, c1 = *(const float4*)(r1 + 4);
    float ssq = 0.f;
#pragma unroll
    for (int c = 0; c < 4; c++) {
      float w00 = w[c * 4], w01 = w[c * 4 + 1], w10 = w[c * 4 + 2], w11 = w[c * 4 + 3];
      float v0 = bias[c] + a0.x * w00 + a0.y * w01 + c0.x * w10 + c0.y * w11;
      float v1 = bias[c] + a0.z * w00 + a0.w * w01 + c0.z * w10 + c0.w * w11;
      float v2 = bias[c] + a1.x * w00 + a1.y * w01 + c1.x * w10 + c1.y * w11;
      float v3 = bias[c] + a1.z * w00 + a1.w * w01 + c1.z * w10 + c1.w * w11;
      ssq += v0 * v0 + v1 * v1 + v2 * v2 + v3 * v3;
      *(unsigned int*)(fb8 + c * 1024 + p0) = pack4(v0, v1, v2, v3);
    }
    for (int off = 32; off > 0; off >>= 1) ssq += __shfl_down(ssq, off);
    if ((tid & 63) == 0) red[tid >> 6] = ssq;
    __syncthreads();
    if (tid == 0) f2[b] = red[0] + red[1] + red[2] + red[3];
  }
}

// ---------------- Kernel 2: fp8 GEMM (16x16x128 mfma_scale) + RBF epilogue ------------
// BM=128, BN=256, BK=128; 8 waves (2M x 4N); ring-3 LDS (144 KiB).
// REGISTER READ-AHEAD: body t MFMAs on frags(t) read last body (X/Y reg sets),
// while issuing 16 ds_reads for frags(t+1) and 6 GLDS staging tile t+2.
// Body top: vmcnt(0) [stage t+1 landed, issued a full body ago] -> s_barrier
// [publishes t+1; frees recycled buffer] -> lgkmcnt(0) [own frags(t) in regs].
// Fragment geometry identical to the round-5 kernel (measured 0 bank conflicts).
#define SWZA(o) ((o) ^ ((((o) >> 12) & 1) << 4))
#define SWZB(o) ((o) ^ ((((o) >> 13) & 1) << 4))
#define TILE_BYTES 49152

#define GLDS(gsrc, ldst)                                                    \
  __builtin_amdgcn_global_load_lds(                                         \
      (__attribute__((address_space(1))) void*)(void*)(gsrc),               \
      (__attribute__((address_space(3))) void*)(ldst), 16, 0, 0)

#define MFMA8(a, b, c)                                                      \
  __builtin_amdgcn_mfma_scale_f32_16x16x128_f8f6f4(                         \
      (a), (b), (c), 0, 0, 0, 0x7f7f7f7fu, 0, 0x7f7f7f7fu)

__device__ __forceinline__ i32x8 read32(const char* p0, const char* p1) {
  i32x4 lo = *(const i32x4*)p0;
  i32x4 hi = *(const i32x4*)p1;
  return __builtin_shufflevector(lo, hi, 0, 1, 2, 3, 4, 5, 6, 7);
}

#define TBODY(PTN, PTS, CA0, CA1, CA2, CA3, CB0, CB1, CB2, CB3,             \
              NA0, NA1, NA2, NA3, NB0, NB1, NB2, NB3, KB)                   \
  {                                                                         \
    asm volatile("s_waitcnt vmcnt(0)" ::: "memory");                        \
    __builtin_amdgcn_sched_barrier(0);                                      \
    __builtin_amdgcn_s_barrier();                                           \
    asm volatile("s_waitcnt lgkmcnt(0)" ::: "memory");                      \
    __builtin_amdgcn_sched_barrier(0);                                      \
    NA0 = read32((PTN) + arlo[0], (PTN) + arhi[0]);                         \
    NA1 = read32((PTN) + arlo[1], (PTN) + arhi[1]);                         \
    NA2 = read32((PTN) + arlo[2], (PTN) + arhi[2]);                         \
    NA3 = read32((PTN) + arlo[3], (PTN) + arhi[3]);                         \
    NB0 = read32((PTN) + brlo[0], (PTN) + brhi[0]);                         \
    NB1 = read32((PTN) + brlo[1], (PTN) + brhi[1]);                         \
    GLDS(agp[0] + (KB), (PTS) + aoff[0]);                                   \
    GLDS(agp[1] + (KB), (PTS) + aoff[1]);                                   \
    GLDS(bgp[0] + (KB), (PTS) + 16384 + boff[0]);                           \
    __builtin_amdgcn_sched_barrier(0);                                      \
    __builtin_amdgcn_s_setprio(1);                                          \
    acc[0][0] = MFMA8(CA0, CB0, acc[0][0]);                                 \
    acc[0][1] = MFMA8(CA0, CB1, acc[0][1]);                                 \
    acc[1][0] = MFMA8(CA1, CB0, acc[1][0]);                                 \
    acc[1][1] = MFMA8(CA1, CB1, acc[1][1]);                                 \
    acc[2][0] = MFMA8(CA2, CB0, acc[2][0]);                                 \
    acc[2][1] = MFMA8(CA2, CB1, acc[2][1]);                                 \
    acc[3][0] = MFMA8(CA3, CB0, acc[3][0]);                                 \
    acc[3][1] = MFMA8(CA3, CB1, acc[3][1]);                                 \
    __builtin_amdgcn_s_setprio(0);                                          \
    __builtin_amdgcn_sched_barrier(0);                                      \
    NB2 = read32((PTN) + brlo[2], (PTN) + brhi[2]);                         \
    NB3 = read32((PTN) + brlo[3], (PTN) + brhi[3]);                         \
    GLDS(bgp[1] + (KB), (PTS) + 16384 + boff[1]);                           \
    GLDS(bgp[2] + (KB), (PTS) + 16384 + boff[2]);                           \
    GLDS(bgp[3] + (KB), (PTS) + 16384 + boff[3]);                           \
    __builtin_amdgcn_sched_barrier(0);                                      \
    __builtin_amdgcn_s_setprio(1);                                          \
    acc[0][2] = MFMA8(CA0, CB2, acc[0][2]);                                 \
    acc[0][3] = MFMA8(CA0, CB3, acc[0][3]);                                 \
    acc[1][2] = MFMA8(CA1, CB2, acc[1][2]);                                 \
    acc[1][3] = MFMA8(CA1, CB3, acc[1][3]);                                 \
    acc[2][2] = MFMA8(CA2, CB2, acc[2][2]);                                 \
    acc[2][3] = MFMA8(CA2, CB3, acc[2][3]);                                 \
    acc[3][2] = MFMA8(CA3, CB3, acc[3][2]);                                 \
    acc[3][3] = MFMA8(CA3, CB3, acc[3][3]);                                 \
    __builtin_amdgcn_s_setprio(0);                                          \
    __builtin_amdgcn_sched_barrier(0);                                      \
  }

__global__ __launch_bounds__(512, 1) void gemm_kv_k(
    const unsigned char* __restrict__ A, const unsigned char* __restrict__ B,
    const float* __restrict__ f2, const float* __restrict__ p2,
    __hip_bfloat16* __restrict__ kv) {
  __shared__ __align__(16) char lds[3 * TILE_BYTES];  // 144 KiB
  const int tid = threadIdx.x;
  const int wave = tid >> 6, lane = tid & 63;
  const int q = lane >> 4, l16 = lane & 15;
  const int wr = wave >> 2, wc = wave & 3;

  // XCD-aware tile swizzle: 256 WGs = 8 XCDs x 32
  const int wg = blockIdx.x;
  const int xcd = wg & 7, loc = wg >> 3;
  const int bm = (xcd & 1) * 8 + (loc & 7);
  const int bn = (xcd >> 1) * 4 + (loc >> 3);

  // staging: linear LDS dest, inverse-swizzled global src (rule #21)
  const unsigned char* agp[2];
  const unsigned char* bgp[4];
  int aoff[2], boff[4];
#pragma unroll
  for (int i = 0; i < 2; i++) {
    int phys = (tid + i * 512) * 16;
    aoff[i] = phys;
    int lg = SWZA(phys);
    int kq = lg >> 12, rw = (lg & 4095) >> 5, kl = lg & 31;
    agp[i] = A + (size_t)(bm * 128 + rw) * 4096 + kq * 32 + kl;
  }
#pragma unroll
  for (int i = 0; i < 4; i++) {
    int phys = (tid + i * 512) * 16;
    boff[i] = phys;
    int lg = SWZB(phys);
    int kq = lg >> 13, rw = (lg & 8191) >> 5, kl = lg & 31;
    bgp[i] = B + (size_t)(bn * 256 + rw) * 4096 + kq * 32 + kl;
  }

  // fragment read addresses (round-5 verified, 0 conflicts)
  int arlo[4], arhi[4], brlo[4], brhi[4];
#pragma unroll
  for (int m = 0; m < 4; m++) {
    int lg = q * 4096 + (wr * 64 + m * 16 + l16) * 32;
    arlo[m] = SWZA(lg);
    arhi[m] = SWZA(lg + 16);
  }
#pragma unroll
  for (int n = 0; n < 4; n++) {
    int lg = q * 8192 + (wc * 64 + n * 16 + l16) * 32;
    brlo[n] = 16384 + SWZB(lg);
    brhi[n] = 16384 + SWZB(lg + 16);
  }

  f32x4 acc[4][4] = {};
  i32x8 Xa0, Xa1, Xa2, Xa3, Xb0, Xb1, Xb2, Xb3;
  i32x8 Ya0, Ya1, Ya2, Ya3, Yb0, Yb1, Yb2, Yb3;

  char* b0 = lds;
  char* b1 = lds + TILE_BYTES;
  char* b2 = lds + 2 * TILE_BYTES;

  // prologue: stage tiles 0 and 1 (K-tile byte stride = 128)
#pragma unroll
  for (int i = 0; i < 2; i++) GLDS(agp[i], b0 + aoff[i]);
#pragma unroll
  for (int i = 0; i < 4; i++) GLDS(bgp[i], b0 + 16384 + boff[i]);
#pragma unroll
  for (int i = 0; i < 2; i++) GLDS(agp[i] + 128, b1 + aoff[i]);
#pragma unroll
  for (int i = 0; i < 4; i++) GLDS(bgp[i] + 128, b1 + 16384 + boff[i]);
  asm volatile("s_waitcnt vmcnt(6)" ::: "memory");  // own tile-0 loads landed
  __builtin_amdgcn_s_barrier();                     // all tile-0 loads landed

  // initial fragments: tile 0 -> X
  Xa0 = read32(b0 + arlo[0], b0 + arhi[0]);
  Xa1 = read32(b0 + arlo[1], b0 + arhi[1]);
  Xa2 = read32(b0 + arlo[2], b0 + arhi[2]);
  Xa3 = read32(b0 + arlo[3], b0 + arhi[3]);
  Xb0 = read32(b0 + brlo[0], b0 + brhi[0]);
  Xb1 = read32(b0 + brlo[1], b0 + brhi[1]);
  Xb2 = read32(b0 + brlo[2], b0 + brhi[2]);
  Xb3 = read32(b0 + brlo[3], b0 + brhi[3]);

#pragma unroll 1
  for (int t = 0; t < 32; t += 2) {
    const int kb2 = ((t + 2) & 31) * 128;  // tail wraps -> dead stages, drained at body top
    const int kb3 = ((t + 3) & 31) * 128;
    // body t: MFMA frags(t)=X, read frags(t+1)->Y from b1, stage t+2 -> b2
    TBODY(b1, b2, Xa0, Xa1, Xa2, Xa3, Xb0, Xb1, Xb2, Xb3,
          Ya0, Ya1, Ya2, Ya3, Yb0, Yb1, Yb2, Yb3, kb2);
    // body t+1: MFMA frags(t+1)=Y, read frags(t+2)->X from b2, stage t+3 -> b0
    TBODY(b2, b0, Ya0, Ya1, Ya2, Ya3, Yb0, Yb1, Yb2, Yb3,
          Xa0, Xa1, Xa2, Xa3, Xb0, Xb1, Xb2, Xb3, kb3);
    char* nb0 = b2; char* nb1 = b0; char* nb2 = b1;
    b0 = nb0; b1 = nb1; b2 = nb2;
  }

  asm volatile("s_waitcnt vmcnt(0) lgkmcnt(0)" ::: "memory");  // drain tail

  // epilogue: kv = bf16(exp(-gamma * max(f2 + p2 - 2*dot, 0)))
  // C/D layout (16x16): col = lane&15, row = (lane>>4)*4 + j
  float p2v[4];
#pragma unroll
  for (int n = 0; n < 4; n++) p2v[n] = p2[bn * 256 + wc * 64 + n * 16 + l16];
#pragma unroll
  for (int m = 0; m < 4; m++) {
#pragma unroll
    for (int j = 0; j < 4; j++) {
      int grow = bm * 128 + wr * 64 + m * 16 + q * 4 + j;
      float f2v = f2[grow];
      __hip_bfloat16* kvp = kv + (size_t)grow * 4096 + bn * 256 + wc * 64 + l16;
#pragma unroll
      for (int n = 0; n < 4; n++) {
        float d2 = fmaxf(f2v + p2v[n] - 2.0f * acc[m][n][j], 0.f);
        kvp[n * 16] = __float2bfloat16(__expf(-GAMMA * d2));
      }
    }
  }
}

// ---------------- Kernel 3: logits = kv @ head_w^T + b; log_softmax (8 rows/block) ----
__global__ __launch_bounds__(256) void head_ls_k(
    const __hip_bfloat16* __restrict__ kv, const float* __restrict__ hw,
    const float* __restrict__ hb, float* __restrict__ out) {
  const int bb = blockIdx.x * 8;
  const int tid = threadIdx.x;
  float part[8][10];
#pragma unroll
  for (int r = 0; r < 8; r++)
#pragma unroll
    for (int c = 0; c < 10; c++) part[r][c] = 0.f;
#pragma unroll
  for (int k = 0; k < 4; k++) {
    int idx = tid + k * 256;
    float4 w[10];
#pragma unroll
    for (int c = 0; c < 10; c++) w[c] = *(const float4*)(hw + c * 4096 + idx * 4);
#pragma unroll
    for (int r = 0; r < 8; r++) {
      ushort4 v = ((const ushort4*)(kv + (size_t)(bb + r) * 4096))[idx];
      float a0 = bf2f(v.x), a1 = bf2f(v.y), a2 = bf2f(v.z), a3 = bf2f(v.w);
#pragma unroll
      for (int c = 0; c < 10; c++)
        part[r][c] += a0 * w[c].x + a1 * w[c].y + a2 * w[c].z + a3 * w[c].w;
    }
  }
#pragma unroll
  for (int r = 0; r < 8; r++)
#pragma unroll
    for (int c = 0; c < 10; c++)
      for (int off = 32; off > 0; off >>= 1) part[r][c] += __shfl_down(part[r][c], off);
  __shared__ float red[4][8][10];
  if ((tid & 63) == 0) {
#pragma unroll
    for (int r = 0; r < 8; r++)
#pragma unroll
      for (int c = 0; c < 10; c++) red[tid >> 6][r][c] = part[r][c];
  }
  __syncthreads();
  if (tid < 8) {
    const int r = tid;
    float l[10], m = -1e30f;
#pragma unroll
    for (int c = 0; c < 10; c++) {
      l[c] = red[0][r][c] + red[1][r][c] + red[2][r][c] + red[3][r][c] + hb[c];
      m = fmaxf(m, l[c]);
    }
    float s = 0.f;
#pragma unroll
    for (int c = 0; c < 10; c++) s += __expf(l[c] - m);
    float lse = logf(s);
#pragma unroll
    for (int c = 0; c < 10; c++) out[(size_t)(bb + r) * 10 + c] = l[c] - m - lse;
  }
}

extern "C" void kernel_launch(void* const* d_in, const int* in_sizes, int n_in,
                              void* d_out, int out_size, void* d_ws, size_t ws_size,
                              hipStream_t stream) {
  const float* x      = (const float*)d_in[0];
  const float* protos = (const float*)d_in[1];
  const float* conv_w = (const float*)d_in[2];
  const float* conv_b = (const float*)d_in[3];
  const float* head_w = (const float*)d_in[4];
  const float* head_b = (const float*)d_in[5];
  float* out = (float*)d_out;
  char* ws = (char*)d_ws;

  unsigned char* pB8  = (unsigned char*)ws;                      // 4096x4096 fp8 = 16 MB
  unsigned char* fA8  = (unsigned char*)(ws + (16u << 20));      // 2048x4096 fp8 =  8 MB
  __hip_bfloat16* kvb = (__hip_bfloat16*)(ws + (24u << 20));     // 2048x4096 bf16 = 16 MB
  float* f2 = (float*)(ws + (40u << 20));                        // 2048 f32
  float* p2 = (float*)(ws + (40u << 20) + 8192);                 // 4096 f32

  hipLaunchKernelGGL(prep_k, dim3(6144), dim3(256), 0, stream,
                     x, conv_w, conv_b, fA8, f2, protos, pB8, p2);
  hipLaunchKernelGGL(gemm_kv_k, dim3(256), dim3(512), 0, stream, fA8, pB8, f2, p2, kvb);
  hipLaunchKernelGGL(head_ls_k, dim3(256), dim3(256), 0, stream, kvb, head_w, head_b, out);
}

// Round 8
// 92.039 us; speedup vs baseline: 1.0403x; 1.0403x over previous
//
#include <hip/hip_runtime.h>
#include <hip/hip_bf16.h>
#include <stdint.h>

#define GAMMA 1e-4f

typedef int i32x4 __attribute__((ext_vector_type(4)));
typedef int i32x8 __attribute__((ext_vector_type(8)));
typedef float f32x4 __attribute__((ext_vector_type(4)));

__device__ __forceinline__ float bf2f(unsigned short u) {
  unsigned int x = ((unsigned int)u) << 16;
  float f; __builtin_memcpy(&f, &x, 4);
  return f;
}

// bit-exact float -> OCP e4m3fn (RNE, satfinite).
__device__ __forceinline__ unsigned char f2e4m3(float x) {
  float a = fabsf(x);
  unsigned char s = x < 0.f ? 0x80 : 0;
  a = fminf(a, 448.f);
  if (a < 0.015625f) {                    // subnormal region, ulp 2^-9
    int q = (int)rintf(a * 512.f);
    return s | (unsigned char)q;
  }
  unsigned int u; __builtin_memcpy(&u, &a, 4);
  u += 0x7FFFFu + ((u >> 20) & 1);        // RNE to 3 mantissa bits
  u &= 0xFFF00000u;
  int e2 = (int)(u >> 23) - 127;
  unsigned int mant = (u >> 20) & 7;
  return s | (unsigned char)(((e2 + 7) << 3) | mant);
}

__device__ __forceinline__ unsigned int pack4(float a, float b, float c, float d) {
  return (unsigned)f2e4m3(a) | ((unsigned)f2e4m3(b) << 8) |
         ((unsigned)f2e4m3(c) << 16) | ((unsigned)f2e4m3(d) << 24);
}

// ---------------- Kernel 1: merged prep (fp8 outputs, fp32 norms) ----------------
__global__ __launch_bounds__(256) void prep_k(
    const float* __restrict__ x, const float* __restrict__ cw,
    const float* __restrict__ cb, unsigned char* __restrict__ fA8,
    float* __restrict__ f2, const float* __restrict__ pr,
    unsigned char* __restrict__ pB8, float* __restrict__ p2) {
  const int tid = threadIdx.x;
  __shared__ float red[4];
  if (blockIdx.x < 4096) {
    const int j = blockIdx.x;
    const float4* src = (const float4*)(pr + (size_t)j * 4096);
    float ssq = 0.f;
    unsigned int w4[4];
#pragma unroll
    for (int k = 0; k < 4; k++) {
      float4 v = src[tid * 4 + k];
      ssq += v.x * v.x + v.y * v.y + v.z * v.z + v.w * v.w;
      w4[k] = pack4(v.x, v.y, v.z, v.w);
    }
    *(uint4*)(pB8 + (size_t)j * 4096 + tid * 16) = make_uint4(w4[0], w4[1], w4[2], w4[3]);
    for (int off = 32; off > 0; off >>= 1) ssq += __shfl_down(ssq, off);
    if ((tid & 63) == 0) red[tid >> 6] = ssq;
    __syncthreads();
    if (tid == 0) p2[j] = red[0] + red[1] + red[2] + red[3];
  } else {
    const int b = blockIdx.x - 4096;
    __shared__ float swb[20];
    if (tid < 16) swb[tid] = cw[tid];
    else if (tid < 20) swb[tid] = cb[tid - 16];
    __syncthreads();
    float w[16], bias[4];
#pragma unroll
    for (int i = 0; i < 16; i++) w[i] = swb[i];
#pragma unroll
    for (int c = 0; c < 4; c++) bias[c] = swb[16 + c];
    const float* xb = x + (size_t)b * 4096;
    unsigned char* fb8 = fA8 + (size_t)b * 4096;
    const int p0 = tid * 4;
    const int h = p0 >> 5, w0 = p0 & 31;
    const float* r0 = xb + (2 * h) * 64 + 2 * w0;
    const float* r1 = r0 + 64;
    float4 a0 = *(const float4*)r0, a1 = *(const float4*)(r0 + 4);
    float4 c0 = *(const float4*)r1, c1 = *(const float4*)(r1 + 4);
    float ssq = 0.f;
#pragma unroll
    for (int c = 0; c < 4; c++) {
      float w00 = w[c * 4], w01 = w[c * 4 + 1], w10 = w[c * 4 + 2], w11 = w[c * 4 + 3];
      float v0 = bias[c] + a0.x * w00 + a0.y * w01 + c0.x * w10 + c0.y * w11;
      float v1 = bias[c] + a0.z * w00 + a0.w * w01 + c0.z * w10 + c0.w * w11;
      float v2 = bias[c] + a1.x * w00 + a1.y * w01 + c1.x * w10 + c1.y * w11;
      float v3 = bias[c] + a1.z * w00 + a1.w * w01 + c1.z * w10 + c1.w * w11;
      ssq += v0 * v0 + v1 * v1 + v2 * v2 + v3 * v3;
      *(unsigned int*)(fb8 + c * 1024 + p0) = pack4(v0, v1, v2, v3);
    }
    for (int off = 32; off > 0; off >>= 1) ssq += __shfl_down(ssq, off);
    if ((tid & 63) == 0) red[tid >> 6] = ssq;
    __syncthreads();
    if (tid == 0) f2[b] = red[0] + red[1] + red[2] + red[3];
  }
}

// ---------------- Kernel 2: fp8 GEMM (16x16x128 mfma_scale) + RBF epilogue ------------
// BM=BN=128, BK=128; 4 waves (2x2); ring-2 double-buffer = 64 KiB -> 2 WGs/CU.
// Independent per-WG barriers: co-resident WG fills this WG's vmcnt/barrier drain
// (m114 mechanism). Body = proven R5 two-phase interleave (0 bank conflicts).
// LDS per buffer: A [4 kq][128 rows][32B] @0 (16KB), B same @16384 (16KB).
// Swizzle: phys = logical ^ (((logical>>12)&1)<<4)  (both sides, rule #21).
#define SWZ(o) ((o) ^ ((((o) >> 12) & 1) << 4))
#define TILE_BYTES 32768

#define GLDS(gsrc, ldst)                                                    \
  __builtin_amdgcn_global_load_lds(                                         \
      (__attribute__((address_space(1))) void*)(void*)(gsrc),               \
      (__attribute__((address_space(3))) void*)(ldst), 16, 0, 0)

#define MFMA8(a, b, c)                                                      \
  __builtin_amdgcn_mfma_scale_f32_16x16x128_f8f6f4(                         \
      (a), (b), (c), 0, 0, 0, 0x7f7f7f7fu, 0, 0x7f7f7f7fu)

__device__ __forceinline__ i32x8 read32(const char* p0, const char* p1) {
  i32x4 lo = *(const i32x4*)p0;
  i32x4 hi = *(const i32x4*)p1;
  return __builtin_shufflevector(lo, hi, 0, 1, 2, 3, 4, 5, 6, 7);
}

// one K-tile: read frags from CUR, stage tile t+1 into NXT at K-byte KB.
#define TBODY(CUR, NXT, KB)                                                 \
  {                                                                         \
    i32x8 av0, av1, av2, av3, bv0, bv1, bv2, bv3;                           \
    __builtin_amdgcn_sched_barrier(0);                                      \
    av0 = read32((CUR) + arlo[0], (CUR) + arhi[0]);                         \
    av1 = read32((CUR) + arlo[1], (CUR) + arhi[1]);                         \
    av2 = read32((CUR) + arlo[2], (CUR) + arhi[2]);                         \
    av3 = read32((CUR) + arlo[3], (CUR) + arhi[3]);                         \
    bv0 = read32((CUR) + brlo[0], (CUR) + brhi[0]);                         \
    bv1 = read32((CUR) + brlo[1], (CUR) + brhi[1]);                         \
    __builtin_amdgcn_sched_barrier(0);                                      \
    GLDS(agp[0] + (KB), (NXT) + aoff[0]);                                   \
    GLDS(agp[1] + (KB), (NXT) + aoff[1]);                                   \
    GLDS(agp[2] + (KB), (NXT) + aoff[2]);                                   \
    GLDS(agp[3] + (KB), (NXT) + aoff[3]);                                   \
    bv2 = read32((CUR) + brlo[2], (CUR) + brhi[2]);                         \
    bv3 = read32((CUR) + brlo[3], (CUR) + brhi[3]);                         \
    GLDS(bgp[0] + (KB), (NXT) + 16384 + boff[0]);                           \
    GLDS(bgp[1] + (KB), (NXT) + 16384 + boff[1]);                           \
    GLDS(bgp[2] + (KB), (NXT) + 16384 + boff[2]);                           \
    GLDS(bgp[3] + (KB), (NXT) + 16384 + boff[3]);                           \
    __builtin_amdgcn_sched_barrier(0);                                      \
    asm volatile("s_waitcnt lgkmcnt(4)" ::: "memory");                      \
    __builtin_amdgcn_sched_barrier(0);                                      \
    __builtin_amdgcn_s_setprio(1);                                          \
    acc[0][0] = MFMA8(av0, bv0, acc[0][0]);                                 \
    acc[0][1] = MFMA8(av0, bv1, acc[0][1]);                                 \
    acc[1][0] = MFMA8(av1, bv0, acc[1][0]);                                 \
    acc[1][1] = MFMA8(av1, bv1, acc[1][1]);                                 \
    acc[2][0] = MFMA8(av2, bv0, acc[2][0]);                                 \
    acc[2][1] = MFMA8(av2, bv1, acc[2][1]);                                 \
    acc[3][0] = MFMA8(av3, bv0, acc[3][0]);                                 \
    acc[3][1] = MFMA8(av3, bv1, acc[3][1]);                                 \
    __builtin_amdgcn_s_setprio(0);                                          \
    __builtin_amdgcn_sched_barrier(0);                                      \
    asm volatile("s_waitcnt lgkmcnt(0)" ::: "memory");                      \
    __builtin_amdgcn_sched_barrier(0);                                      \
    __builtin_amdgcn_s_setprio(1);                                          \
    acc[0][2] = MFMA8(av0, bv2, acc[0][2]);                                 \
    acc[0][3] = MFMA8(av0, bv3, acc[0][3]);                                 \
    acc[1][2] = MFMA8(av1, bv2, acc[1][2]);                                 \
    acc[1][3] = MFMA8(av1, bv3, acc[1][3]);                                 \
    acc[2][2] = MFMA8(av2, bv2, acc[2][2]);                                 \
    acc[2][3] = MFMA8(av2, bv3, acc[2][3]);                                 \
    acc[3][2] = MFMA8(av3, bv2, acc[3][2]);                                 \
    acc[3][3] = MFMA8(av3, bv3, acc[3][3]);                                 \
    __builtin_amdgcn_s_setprio(0);                                          \
    __builtin_amdgcn_sched_barrier(0);                                      \
    asm volatile("s_waitcnt vmcnt(0)" ::: "memory");                        \
    __builtin_amdgcn_sched_barrier(0);                                      \
    __builtin_amdgcn_s_barrier();                                           \
  }

__global__ __launch_bounds__(256, 2) void gemm_kv_k(
    const unsigned char* __restrict__ A, const unsigned char* __restrict__ B,
    const float* __restrict__ f2, const float* __restrict__ p2,
    __hip_bfloat16* __restrict__ kv) {
  __shared__ __align__(16) char lds[2 * TILE_BYTES];  // 64 KiB -> 2 WGs/CU
  const int tid = threadIdx.x;
  const int wave = tid >> 6, lane = tid & 63;
  const int q = lane >> 4, l16 = lane & 15;
  const int wr = wave >> 1, wc = wave & 1;

  // bijective XCD swizzle: 512 WGs = 8 XCDs x 64; each XCD owns a 4-wide bn strip
  // (512 cols x 4096 B = 2 MB of B -> L2-resident) spanning all bm.
  const int wg = blockIdx.x;
  const int xcd = wg & 7, loc = wg >> 3;
  const int bm = loc >> 2;             // 0..15
  const int bn = xcd * 4 + (loc & 3);  // 0..31

  // staging: linear LDS dest, inverse-swizzled global src (rule #21)
  const unsigned char* agp[4];
  const unsigned char* bgp[4];
  int aoff[4], boff[4];
#pragma unroll
  for (int i = 0; i < 4; i++) {
    int phys = (tid + i * 256) * 16;   // [0,16384)
    aoff[i] = phys;
    boff[i] = phys;
    int lg = SWZ(phys);
    int kq = lg >> 12, rw = (lg & 4095) >> 5, kl = lg & 31;
    agp[i] = A + (size_t)(bm * 128 + rw) * 4096 + kq * 32 + kl;
    bgp[i] = B + (size_t)(bn * 128 + rw) * 4096 + kq * 32 + kl;
  }

  // fragment read addresses (R5-verified pattern, 0 conflicts)
  int arlo[4], arhi[4], brlo[4], brhi[4];
#pragma unroll
  for (int m = 0; m < 4; m++) {
    int lg = q * 4096 + (wr * 64 + m * 16 + l16) * 32;
    arlo[m] = SWZ(lg);
    arhi[m] = SWZ(lg + 16);
  }
#pragma unroll
  for (int n = 0; n < 4; n++) {
    int lg = q * 4096 + (wc * 64 + n * 16 + l16) * 32;
    brlo[n] = 16384 + SWZ(lg);
    brhi[n] = 16384 + SWZ(lg + 16);
  }

  f32x4 acc[4][4] = {};

  char* buf0 = lds;
  char* buf1 = lds + TILE_BYTES;

  // prologue: stage tile 0 into buf0
#pragma unroll
  for (int i = 0; i < 4; i++) GLDS(agp[i], buf0 + aoff[i]);
#pragma unroll
  for (int i = 0; i < 4; i++) GLDS(bgp[i], buf0 + 16384 + boff[i]);
  asm volatile("s_waitcnt vmcnt(0)" ::: "memory");
  __builtin_amdgcn_s_barrier();

#pragma unroll 1
  for (int t = 0; t < 32; t += 2) {
    const int kb1 = ((t + 1) & 31) * 128;
    const int kb2 = ((t + 2) & 31) * 128;  // t=30 -> stages tile 0 (dead), drained in body
    TBODY(buf0, buf1, kb1);
    TBODY(buf1, buf0, kb2);
  }

  // epilogue: kv = bf16(exp(-gamma * max(f2 + p2 - 2*dot, 0)))
  // C/D layout (16x16): col = lane&15, row = (lane>>4)*4 + j
  float p2v[4];
#pragma unroll
  for (int n = 0; n < 4; n++) p2v[n] = p2[bn * 128 + wc * 64 + n * 16 + l16];
#pragma unroll
  for (int m = 0; m < 4; m++) {
#pragma unroll
    for (int j = 0; j < 4; j++) {
      int grow = bm * 128 + wr * 64 + m * 16 + q * 4 + j;
      float f2v = f2[grow];
      __hip_bfloat16* kvp = kv + (size_t)grow * 4096 + bn * 128 + wc * 64 + l16;
#pragma unroll
      for (int n = 0; n < 4; n++) {
        float d2 = fmaxf(f2v + p2v[n] - 2.0f * acc[m][n][j], 0.f);
        kvp[n * 16] = __float2bfloat16(__expf(-GAMMA * d2));
      }
    }
  }
}

// ---------------- Kernel 3: logits = kv @ head_w^T + b; log_softmax (8 rows/block) ----
__global__ __launch_bounds__(256) void head_ls_k(
    const __hip_bfloat16* __restrict__ kv, const float* __restrict__ hw,
    const float* __restrict__ hb, float* __restrict__ out) {
  const int bb = blockIdx.x * 8;
  const int tid = threadIdx.x;
  float part[8][10];
#pragma unroll
  for (int r = 0; r < 8; r++)
#pragma unroll
    for (int c = 0; c < 10; c++) part[r][c] = 0.f;
#pragma unroll
  for (int k = 0; k < 4; k++) {
    int idx = tid + k * 256;
    float4 w[10];
#pragma unroll
    for (int c = 0; c < 10; c++) w[c] = *(const float4*)(hw + c * 4096 + idx * 4);
#pragma unroll
    for (int r = 0; r < 8; r++) {
      ushort4 v = ((const ushort4*)(kv + (size_t)(bb + r) * 4096))[idx];
      float a0 = bf2f(v.x), a1 = bf2f(v.y), a2 = bf2f(v.z), a3 = bf2f(v.w);
#pragma unroll
      for (int c = 0; c < 10; c++)
        part[r][c] += a0 * w[c].x + a1 * w[c].y + a2 * w[c].z + a3 * w[c].w;
    }
  }
#pragma unroll
  for (int r = 0; r < 8; r++)
#pragma unroll
    for (int c = 0; c < 10; c++)
      for (int off = 32; off > 0; off >>= 1) part[r][c] += __shfl_down(part[r][c], off);
  __shared__ float red[4][8][10];
  if ((tid & 63) == 0) {
#pragma unroll
    for (int r = 0; r < 8; r++)
#pragma unroll
      for (int c = 0; c < 10; c++) red[tid >> 6][r][c] = part[r][c];
  }
  __syncthreads();
  if (tid < 8) {
    const int r = tid;
    float l[10], m = -1e30f;
#pragma unroll
    for (int c = 0; c < 10; c++) {
      l[c] = red[0][r][c] + red[1][r][c] + red[2][r][c] + red[3][r][c] + hb[c];
      m = fmaxf(m, l[c]);
    }
    float s = 0.f;
#pragma unroll
    for (int c = 0; c < 10; c++) s += __expf(l[c] - m);
    float lse = logf(s);
#pragma unroll
    for (int c = 0; c < 10; c++) out[(size_t)(bb + r) * 10 + c] = l[c] - m - lse;
  }
}

extern "C" void kernel_launch(void* const* d_in, const int* in_sizes, int n_in,
                              void* d_out, int out_size, void* d_ws, size_t ws_size,
                              hipStream_t stream) {
  const float* x      = (const float*)d_in[0];
  const float* protos = (const float*)d_in[1];
  const float* conv_w = (const float*)d_in[2];
  const float* conv_b = (const float*)d_in[3];
  const float* head_w = (const float*)d_in[4];
  const float* head_b = (const float*)d_in[5];
  float* out = (float*)d_out;
  char* ws = (char*)d_ws;

  unsigned char* pB8  = (unsigned char*)ws;                      // 4096x4096 fp8 = 16 MB
  unsigned char* fA8  = (unsigned char*)(ws + (16u << 20));      // 2048x4096 fp8 =  8 MB
  __hip_bfloat16* kvb = (__hip_bfloat16*)(ws + (24u << 20));     // 2048x4096 bf16 = 16 MB
  float* f2 = (float*)(ws + (40u << 20));                        // 2048 f32
  float* p2 = (float*)(ws + (40u << 20) + 8192);                 // 4096 f32

  hipLaunchKernelGGL(prep_k, dim3(6144), dim3(256), 0, stream,
                     x, conv_w, conv_b, fA8, f2, protos, pB8, p2);
  hipLaunchKernelGGL(gemm_kv_k, dim3(512), dim3(256), 0, stream, fA8, pB8, f2, p2, kvb);
  hipLaunchKernelGGL(head_ls_k, dim3(256), dim3(256), 0, stream, kvb, head_w, head_b, out);
}

// Round 9
// 87.567 us; speedup vs baseline: 1.0934x; 1.0511x over previous
//
#include <hip/hip_runtime.h>
#include <hip/hip_bf16.h>
#include <stdint.h>

#define GAMMA 1e-4f

typedef int i32x4 __attribute__((ext_vector_type(4)));
typedef int i32x8 __attribute__((ext_vector_type(8)));
typedef float f32x4 __attribute__((ext_vector_type(4)));

__device__ __forceinline__ float bf2f(unsigned short u) {
  unsigned int x = ((unsigned int)u) << 16;
  float f; __builtin_memcpy(&f, &x, 4);
  return f;
}

// bit-exact float -> OCP e4m3fn (RNE, satfinite).
__device__ __forceinline__ unsigned char f2e4m3(float x) {
  float a = fabsf(x);
  unsigned char s = x < 0.f ? 0x80 : 0;
  a = fminf(a, 448.f);
  if (a < 0.015625f) {                    // subnormal region, ulp 2^-9
    int q = (int)rintf(a * 512.f);
    return s | (unsigned char)q;
  }
  unsigned int u; __builtin_memcpy(&u, &a, 4);
  u += 0x7FFFFu + ((u >> 20) & 1);        // RNE to 3 mantissa bits
  u &= 0xFFF00000u;
  int e2 = (int)(u >> 23) - 127;
  unsigned int mant = (u >> 20) & 7;
  return s | (unsigned char)(((e2 + 7) << 3) | mant);
}

__device__ __forceinline__ unsigned int pack4(float a, float b, float c, float d) {
  return (unsigned)f2e4m3(a) | ((unsigned)f2e4m3(b) << 8) |
         ((unsigned)f2e4m3(c) << 16) | ((unsigned)f2e4m3(d) << 24);
}

// ---------------- Kernel 1: merged prep (fp8 outputs, fp32 norms) ----------------
__global__ __launch_bounds__(256) void prep_k(
    const float* __restrict__ x, const float* __restrict__ cw,
    const float* __restrict__ cb, unsigned char* __restrict__ fA8,
    float* __restrict__ f2, const float* __restrict__ pr,
    unsigned char* __restrict__ pB8, float* __restrict__ p2) {
  const int tid = threadIdx.x;
  __shared__ float red[4];
  if (blockIdx.x < 4096) {
    const int j = blockIdx.x;
    const float4* src = (const float4*)(pr + (size_t)j * 4096);
    float ssq = 0.f;
    unsigned int w4[4];
#pragma unroll
    for (int k = 0; k < 4; k++) {
      float4 v = src[tid * 4 + k];
      ssq += v.x * v.x + v.y * v.y + v.z * v.z + v.w * v.w;
      w4[k] = pack4(v.x, v.y, v.z, v.w);
    }
    *(uint4*)(pB8 + (size_t)j * 4096 + tid * 16) = make_uint4(w4[0], w4[1], w4[2], w4[3]);
    for (int off = 32; off > 0; off >>= 1) ssq += __shfl_down(ssq, off);
    if ((tid & 63) == 0) red[tid >> 6] = ssq;
    __syncthreads();
    if (tid == 0) p2[j] = red[0] + red[1] + red[2] + red[3];
  } else {
    const int b = blockIdx.x - 4096;
    __shared__ float swb[20];
    if (tid < 16) swb[tid] = cw[tid];
    else if (tid < 20) swb[tid] = cb[tid - 16];
    __syncthreads();
    float w[16], bias[4];
#pragma unroll
    for (int i = 0; i < 16; i++) w[i] = swb[i];
#pragma unroll
    for (int c = 0; c < 4; c++) bias[c] = swb[16 + c];
    const float* xb = x + (size_t)b * 4096;
    unsigned char* fb8 = fA8 + (size_t)b * 4096;
    const int p0 = tid * 4;
    const int h = p0 >> 5, w0 = p0 & 31;
    const float* r0 = xb + (2 * h) * 64 + 2 * w0;
    const float* r1 = r0 + 64;
    float4 a0 = *(const float4*)r0, a1 = *(const float4*)(r0 + 4);
    float4 c0 = *(const float4*)r1, c1 = *(const float4*)(r1 + 4);
    float ssq = 0.f;
#pragma unroll
    for (int c = 0; c < 4; c++) {
      float w00 = w[c * 4], w01 = w[c * 4 + 1], w10 = w[c * 4 + 2], w11 = w[c * 4 + 3];
      float v0 = bias[c] + a0.x * w00 + a0.y * w01 + c0.x * w10 + c0.y * w11;
      float v1 = bias[c] + a0.z * w00 + a0.w * w01 + c0.z * w10 + c0.w * w11;
      float v2 = bias[c] + a1.x * w00 + a1.y * w01 + c1.x * w10 + c1.y * w11;
      float v3 = bias[c] + a1.z * w00 + a1.w * w01 + c1.z * w10 + c1.w * w11;
      ssq += v0 * v0 + v1 * v1 + v2 * v2 + v3 * v3;
      *(unsigned int*)(fb8 + c * 1024 + p0) = pack4(v0, v1, v2, v3);
    }
    for (int off = 32; off > 0; off >>= 1) ssq += __shfl_down(ssq, off);
    if ((tid & 63) == 0) red[tid >> 6] = ssq;
    __syncthreads();
    if (tid == 0) f2[b] = red[0] + red[1] + red[2] + red[3];
  }
}

// ---------------- Kernel 2: fp8 GEMM (16x16x128 mfma_scale) + RBF epilogue ------------
// BM=128, BN=256, BK=128; 8 waves (2M x 4N); ring-3 LDS (144 KiB); 1 WG/CU.
// m201-style FINE PHASES: per K-tile, 4 quadrant phases, each =
//   {issue this phase's ds_reads || GLDS -> s_barrier -> lgkmcnt(0) ->
//    setprio(1) + 4 MFMA + setprio(0)}
// so each wave's reads complete under the barrier wait while other waves MFMA.
// vmcnt(6) once per tile before the closing barrier (tile t+1 landed; t+2 in flight).
// Fragment geometry identical to round 5 (measured 0 bank conflicts).
#define SWZA(o) ((o) ^ ((((o) >> 12) & 1) << 4))
#define SWZB(o) ((o) ^ ((((o) >> 13) & 1) << 4))
#define TILE_BYTES 49152

#define GLDS(gsrc, ldst)                                                    \
  __builtin_amdgcn_global_load_lds(                                         \
      (__attribute__((address_space(1))) void*)(void*)(gsrc),               \
      (__attribute__((address_space(3))) void*)(ldst), 16, 0, 0)

#define MFMA8(a, b, c)                                                      \
  __builtin_amdgcn_mfma_scale_f32_16x16x128_f8f6f4(                         \
      (a), (b), (c), 0, 0, 0, 0x7f7f7f7fu, 0, 0x7f7f7f7fu)

__device__ __forceinline__ i32x8 read32(const char* p0, const char* p1) {
  i32x4 lo = *(const i32x4*)p0;
  i32x4 hi = *(const i32x4*)p1;
  return __builtin_shufflevector(lo, hi, 0, 1, 2, 3, 4, 5, 6, 7);
}

#define SB __builtin_amdgcn_sched_barrier(0)
#define LGKM0 asm volatile("s_waitcnt lgkmcnt(0)" ::: "memory")

// one K-tile from CUR, staging tile t+2 into STG at K-byte KB
#define TBODY(CUR, STG, KB)                                                 \
  {                                                                         \
    i32x8 av0, av1, av2, av3, bv0, bv1, bv2, bv3;                           \
    /* ---- phase 0: Q00 ---- */                                            \
    SB;                                                                     \
    av0 = read32((CUR) + arlo[0], (CUR) + arhi[0]);                         \
    av1 = read32((CUR) + arlo[1], (CUR) + arhi[1]);                         \
    bv0 = read32((CUR) + brlo[0], (CUR) + brhi[0]);                         \
    bv1 = read32((CUR) + brlo[1], (CUR) + brhi[1]);                         \
    SB;                                                                     \
    GLDS(agp[0] + (KB), (STG) + aoff[0]);                                   \
    GLDS(agp[1] + (KB), (STG) + aoff[1]);                                   \
    SB;                                                                     \
    __builtin_amdgcn_s_barrier();                                           \
    LGKM0; SB;                                                              \
    __builtin_amdgcn_s_setprio(1);                                          \
    acc[0][0] = MFMA8(av0, bv0, acc[0][0]);                                 \
    acc[0][1] = MFMA8(av0, bv1, acc[0][1]);                                 \
    acc[1][0] = MFMA8(av1, bv0, acc[1][0]);                                 \
    acc[1][1] = MFMA8(av1, bv1, acc[1][1]);                                 \
    __builtin_amdgcn_s_setprio(0);                                          \
    SB;                                                                     \
    /* ---- phase 1: Q10 ---- */                                            \
    av2 = read32((CUR) + arlo[2], (CUR) + arhi[2]);                         \
    av3 = read32((CUR) + arlo[3], (CUR) + arhi[3]);                         \
    SB;                                                                     \
    GLDS(bgp[0] + (KB), (STG) + 16384 + boff[0]);                           \
    GLDS(bgp[1] + (KB), (STG) + 16384 + boff[1]);                           \
    SB;                                                                     \
    __builtin_amdgcn_s_barrier();                                           \
    LGKM0; SB;                                                              \
    __builtin_amdgcn_s_setprio(1);                                          \
    acc[2][0] = MFMA8(av2, bv0, acc[2][0]);                                 \
    acc[2][1] = MFMA8(av2, bv1, acc[2][1]);                                 \
    acc[3][0] = MFMA8(av3, bv0, acc[3][0]);                                 \
    acc[3][1] = MFMA8(av3, bv1, acc[3][1]);                                 \
    __builtin_amdgcn_s_setprio(0);                                          \
    SB;                                                                     \
    /* ---- phase 2: Q01 ---- */                                            \
    bv2 = read32((CUR) + brlo[2], (CUR) + brhi[2]);                         \
    bv3 = read32((CUR) + brlo[3], (CUR) + brhi[3]);                         \
    SB;                                                                     \
    GLDS(bgp[2] + (KB), (STG) + 16384 + boff[2]);                           \
    GLDS(bgp[3] + (KB), (STG) + 16384 + boff[3]);                           \
    SB;                                                                     \
    __builtin_amdgcn_s_barrier();                                           \
    LGKM0; SB;                                                              \
    __builtin_amdgcn_s_setprio(1);                                          \
    acc[0][2] = MFMA8(av0, bv2, acc[0][2]);                                 \
    acc[0][3] = MFMA8(av0, bv3, acc[0][3]);                                 \
    acc[1][2] = MFMA8(av1, bv2, acc[1][2]);                                 \
    acc[1][3] = MFMA8(av1, bv3, acc[1][3]);                                 \
    __builtin_amdgcn_s_setprio(0);                                          \
    SB;                                                                     \
    /* ---- phase 3: Q11 + tile close ---- */                               \
    __builtin_amdgcn_s_barrier();                                           \
    __builtin_amdgcn_s_setprio(1);                                          \
    acc[2][2] = MFMA8(av2, bv2, acc[2][2]);                                 \
    acc[2][3] = MFMA8(av2, bv3, acc[2][3]);                                 \
    acc[3][2] = MFMA8(av3, bv2, acc[3][2]);                                 \
    acc[3][3] = MFMA8(av3, bv3, acc[3][3]);                                 \
    __builtin_amdgcn_s_setprio(0);                                          \
    SB;                                                                     \
    asm volatile("s_waitcnt vmcnt(6)" ::: "memory");                        \
    SB;                                                                     \
    __builtin_amdgcn_s_barrier();                                           \
  }

__global__ __launch_bounds__(512, 1) void gemm_kv_k(
    const unsigned char* __restrict__ A, const unsigned char* __restrict__ B,
    const float* __restrict__ f2, const float* __restrict__ p2,
    __hip_bfloat16* __restrict__ kv) {
  __shared__ __align__(16) char lds[3 * TILE_BYTES];  // 144 KiB
  const int tid = threadIdx.x;
  const int wave = tid >> 6, lane = tid & 63;
  const int q = lane >> 4, l16 = lane & 15;
  const int wr = wave >> 2, wc = wave & 3;

  // XCD-aware tile swizzle: 256 WGs = 8 XCDs x 32
  const int wg = blockIdx.x;
  const int xcd = wg & 7, loc = wg >> 3;
  const int bm = (xcd & 1) * 8 + (loc & 7);
  const int bn = (xcd >> 1) * 4 + (loc >> 3);

  // staging: linear LDS dest, inverse-swizzled global src (rule #21)
  const unsigned char* agp[2];
  const unsigned char* bgp[4];
  int aoff[2], boff[4];
#pragma unroll
  for (int i = 0; i < 2; i++) {
    int phys = (tid + i * 512) * 16;
    aoff[i] = phys;
    int lg = SWZA(phys);
    int kq = lg >> 12, rw = (lg & 4095) >> 5, kl = lg & 31;
    agp[i] = A + (size_t)(bm * 128 + rw) * 4096 + kq * 32 + kl;
  }
#pragma unroll
  for (int i = 0; i < 4; i++) {
    int phys = (tid + i * 512) * 16;
    boff[i] = phys;
    int lg = SWZB(phys);
    int kq = lg >> 13, rw = (lg & 8191) >> 5, kl = lg & 31;
    bgp[i] = B + (size_t)(bn * 256 + rw) * 4096 + kq * 32 + kl;
  }

  // fragment read addresses (round-5 verified, 0 conflicts)
  int arlo[4], arhi[4], brlo[4], brhi[4];
#pragma unroll
  for (int m = 0; m < 4; m++) {
    int lg = q * 4096 + (wr * 64 + m * 16 + l16) * 32;
    arlo[m] = SWZA(lg);
    arhi[m] = SWZA(lg + 16);
  }
#pragma unroll
  for (int n = 0; n < 4; n++) {
    int lg = q * 8192 + (wc * 64 + n * 16 + l16) * 32;
    brlo[n] = 16384 + SWZB(lg);
    brhi[n] = 16384 + SWZB(lg + 16);
  }

  f32x4 acc[4][4] = {};

  char* b0 = lds;
  char* b1 = lds + TILE_BYTES;
  char* b2 = lds + 2 * TILE_BYTES;

  // prologue: stage tiles 0 and 1 (K-tile byte stride = 128)
#pragma unroll
  for (int i = 0; i < 2; i++) GLDS(agp[i], b0 + aoff[i]);
#pragma unroll
  for (int i = 0; i < 4; i++) GLDS(bgp[i], b0 + 16384 + boff[i]);
#pragma unroll
  for (int i = 0; i < 2; i++) GLDS(agp[i] + 128, b1 + aoff[i]);
#pragma unroll
  for (int i = 0; i < 4; i++) GLDS(bgp[i] + 128, b1 + 16384 + boff[i]);
  asm volatile("s_waitcnt vmcnt(6)" ::: "memory");  // own tile-0 loads landed
  __builtin_amdgcn_s_barrier();                     // all tile-0 loads landed

#pragma unroll 1
  for (int t = 0; t < 32; ++t) {
    const int kb2 = ((t + 2) & 31) * 128;  // tail wraps -> dead stages (drained at end)
    TBODY(b0, b2, kb2);
    char* nb0 = b1; char* nb1 = b2; char* nb2 = b0;
    b0 = nb0; b1 = nb1; b2 = nb2;
  }

  asm volatile("s_waitcnt vmcnt(0) lgkmcnt(0)" ::: "memory");  // drain dead tail stages

  // epilogue: kv = bf16(exp(-gamma * max(f2 + p2 - 2*dot, 0)))
  // C/D layout (16x16): col = lane&15, row = (lane>>4)*4 + j
  float p2v[4];
#pragma unroll
  for (int n = 0; n < 4; n++) p2v[n] = p2[bn * 256 + wc * 64 + n * 16 + l16];
#pragma unroll
  for (int m = 0; m < 4; m++) {
#pragma unroll
    for (int j = 0; j < 4; j++) {
      int grow = bm * 128 + wr * 64 + m * 16 + q * 4 + j;
      float f2v = f2[grow];
      __hip_bfloat16* kvp = kv + (size_t)grow * 4096 + bn * 256 + wc * 64 + l16;
#pragma unroll
      for (int n = 0; n < 4; n++) {
        float d2 = fmaxf(f2v + p2v[n] - 2.0f * acc[m][n][j], 0.f);
        kvp[n * 16] = __float2bfloat16(__expf(-GAMMA * d2));
      }
    }
  }
}

// ---------------- Kernel 3: logits = kv @ head_w^T + b; log_softmax (8 rows/block) ----
__global__ __launch_bounds__(256) void head_ls_k(
    const __hip_bfloat16* __restrict__ kv, const float* __restrict__ hw,
    const float* __restrict__ hb, float* __restrict__ out) {
  const int bb = blockIdx.x * 8;
  const int tid = threadIdx.x;
  float part[8][10];
#pragma unroll
  for (int r = 0; r < 8; r++)
#pragma unroll
    for (int c = 0; c < 10; c++) part[r][c] = 0.f;
#pragma unroll
  for (int k = 0; k < 4; k++) {
    int idx = tid + k * 256;
    float4 w[10];
#pragma unroll
    for (int c = 0; c < 10; c++) w[c] = *(const float4*)(hw + c * 4096 + idx * 4);
#pragma unroll
    for (int r = 0; r < 8; r++) {
      ushort4 v = ((const ushort4*)(kv + (size_t)(bb + r) * 4096))[idx];
      float a0 = bf2f(v.x), a1 = bf2f(v.y), a2 = bf2f(v.z), a3 = bf2f(v.w);
#pragma unroll
      for (int c = 0; c < 10; c++)
        part[r][c] += a0 * w[c].x + a1 * w[c].y + a2 * w[c].z + a3 * w[c].w;
    }
  }
#pragma unroll
  for (int r = 0; r < 8; r++)
#pragma unroll
    for (int c = 0; c < 10; c++)
      for (int off = 32; off > 0; off >>= 1) part[r][c] += __shfl_down(part[r][c], off);
  __shared__ float red[4][8][10];
  if ((tid & 63) == 0) {
#pragma unroll
    for (int r = 0; r < 8; r++)
#pragma unroll
      for (int c = 0; c < 10; c++) red[tid >> 6][r][c] = part[r][c];
  }
  __syncthreads();
  if (tid < 8) {
    const int r = tid;
    float l[10], m = -1e30f;
#pragma unroll
    for (int c = 0; c < 10; c++) {
      l[c] = red[0][r][c] + red[1][r][c] + red[2][r][c] + red[3][r][c] + hb[c];
      m = fmaxf(m, l[c]);
    }
    float s = 0.f;
#pragma unroll
    for (int c = 0; c < 10; c++) s += __expf(l[c] - m);
    float lse = logf(s);
#pragma unroll
    for (int c = 0; c < 10; c++) out[(size_t)(bb + r) * 10 + c] = l[c] - m - lse;
  }
}

extern "C" void kernel_launch(void* const* d_in, const int* in_sizes, int n_in,
                              void* d_out, int out_size, void* d_ws, size_t ws_size,
                              hipStream_t stream) {
  const float* x      = (const float*)d_in[0];
  const float* protos = (const float*)d_in[1];
  const float* conv_w = (const float*)d_in[2];
  const float* conv_b = (const float*)d_in[3];
  const float* head_w = (const float*)d_in[4];
  const float* head_b = (const float*)d_in[5];
  float* out = (float*)d_out;
  char* ws = (char*)d_ws;

  unsigned char* pB8  = (unsigned char*)ws;                      // 4096x4096 fp8 = 16 MB
  unsigned char* fA8  = (unsigned char*)(ws + (16u << 20));      // 2048x4096 fp8 =  8 MB
  __hip_bfloat16* kvb = (__hip_bfloat16*)(ws + (24u << 20));     // 2048x4096 bf16 = 16 MB
  float* f2 = (float*)(ws + (40u << 20));                        // 2048 f32
  float* p2 = (float*)(ws + (40u << 20) + 8192);                 // 4096 f32

  hipLaunchKernelGGL(prep_k, dim3(6144), dim3(256), 0, stream,
                     x, conv_w, conv_b, fA8, f2, protos, pB8, p2);
  hipLaunchKernelGGL(gemm_kv_k, dim3(256), dim3(512), 0, stream, fA8, pB8, f2, p2, kvb);
  hipLaunchKernelGGL(head_ls_k, dim3(256), dim3(256), 0, stream, kvb, head_w, head_b, out);
}

// Round 10
// 80.801 us; speedup vs baseline: 1.1849x; 1.0837x over previous
//
#include <hip/hip_runtime.h>
#include <hip/hip_bf16.h>
#include <stdint.h>

#define GAMMA 1e-4f

typedef int i32x4 __attribute__((ext_vector_type(4)));
typedef int i32x8 __attribute__((ext_vector_type(8)));
typedef float f32x4 __attribute__((ext_vector_type(4)));

__device__ __forceinline__ float bf2f(unsigned short u) {
  unsigned int x = ((unsigned int)u) << 16;
  float f; __builtin_memcpy(&f, &x, 4);
  return f;
}

// bit-exact float -> OCP e4m3fn (RNE, satfinite).
__device__ __forceinline__ unsigned char f2e4m3(float x) {
  float a = fabsf(x);
  unsigned char s = x < 0.f ? 0x80 : 0;
  a = fminf(a, 448.f);
  if (a < 0.015625f) {                    // subnormal region, ulp 2^-9
    int q = (int)rintf(a * 512.f);
    return s | (unsigned char)q;
  }
  unsigned int u; __builtin_memcpy(&u, &a, 4);
  u += 0x7FFFFu + ((u >> 20) & 1);        // RNE to 3 mantissa bits
  u &= 0xFFF00000u;
  int e2 = (int)(u >> 23) - 127;
  unsigned int mant = (u >> 20) & 7;
  return s | (unsigned char)(((e2 + 7) << 3) | mant);
}

__device__ __forceinline__ unsigned int pack4(float a, float b, float c, float d) {
  return (unsigned)f2e4m3(a) | ((unsigned)f2e4m3(b) << 8) |
         ((unsigned)f2e4m3(c) << 16) | ((unsigned)f2e4m3(d) << 24);
}

// ---------------- Kernel 1: merged prep (fp8 outputs, fp32 norms) ----------------
__global__ __launch_bounds__(256) void prep_k(
    const float* __restrict__ x, const float* __restrict__ cw,
    const float* __restrict__ cb, unsigned char* __restrict__ fA8,
    float* __restrict__ f2, const float* __restrict__ pr,
    unsigned char* __restrict__ pB8, float* __restrict__ p2) {
  const int tid = threadIdx.x;
  __shared__ float red[4];
  if (blockIdx.x < 4096) {
    const int j = blockIdx.x;
    const float4* src = (const float4*)(pr + (size_t)j * 4096);
    float ssq = 0.f;
    unsigned int w4[4];
#pragma unroll
    for (int k = 0; k < 4; k++) {
      float4 v = src[tid * 4 + k];
      ssq += v.x * v.x + v.y * v.y + v.z * v.z + v.w * v.w;
      w4[k] = pack4(v.x, v.y, v.z, v.w);
    }
    *(uint4*)(pB8 + (size_t)j * 4096 + tid * 16) = make_uint4(w4[0], w4[1], w4[2], w4[3]);
    for (int off = 32; off > 0; off >>= 1) ssq += __shfl_down(ssq, off);
    if ((tid & 63) == 0) red[tid >> 6] = ssq;
    __syncthreads();
    if (tid == 0) p2[j] = red[0] + red[1] + red[2] + red[3];
  } else {
    const int b = blockIdx.x - 4096;
    __shared__ float swb[20];
    if (tid < 16) swb[tid] = cw[tid];
    else if (tid < 20) swb[tid] = cb[tid - 16];
    __syncthreads();
    float w[16], bias[4];
#pragma unroll
    for (int i = 0; i < 16; i++) w[i] = swb[i];
#pragma unroll
    for (int c = 0; c < 4; c++) bias[c] = swb[16 + c];
    const float* xb = x + (size_t)b * 4096;
    unsigned char* fb8 = fA8 + (size_t)b * 4096;
    const int p0 = tid * 4;
    const int h = p0 >> 5, w0 = p0 & 31;
    const float* r0 = xb + (2 * h) * 64 + 2 * w0;
    const float* r1 = r0 + 64;
    float4 a0 = *(const float4*)r0, a1 = *(const float4*)(r0 + 4);
    float4 c0 = *(const float4*)r1, c1 = *(const float4*)(r1 + 4);
    float ssq = 0.f;
#pragma unroll
    for (int c = 0; c < 4; c++) {
      float w00 = w[c * 4], w01 = w[c * 4 + 1], w10 = w[c * 4 + 2], w11 = w[c * 4 + 3];
      float v0 = bias[c] + a0.x * w00 + a0.y * w01 + c0.x * w10 + c0.y * w11;
      float v1 = bias[c] + a0.z * w00 + a0.w * w01 + c0.z * w10 + c0.w * w11;
      float v2 = bias[c] + a1.x * w00 + a1.y * w01 + c1.x * w10 + c1.y * w11;
      float v3 = bias[c] + a1.z * w00 + a1.w * w01 + c1.z * w10 + c1.w * w11;
      ssq += v0 * v0 + v1 * v1 + v2 * v2 + v3 * v3;
      *(unsigned int*)(fb8 + c * 1024 + p0) = pack4(v0, v1, v2, v3);
    }
    for (int off = 32; off > 0; off >>= 1) ssq += __shfl_down(ssq, off);
    if ((tid & 63) == 0) red[tid >> 6] = ssq;
    __syncthreads();
    if (tid == 0) f2[b] = red[0] + red[1] + red[2] + red[3];
  }
}

// ---------------- Kernel 2: fp8 GEMM (16x16x128 mfma_scale) + RBF epilogue ------------
// (byte-identical to round 9 — fine-phase m201-style schedule)
#define SWZA(o) ((o) ^ ((((o) >> 12) & 1) << 4))
#define SWZB(o) ((o) ^ ((((o) >> 13) & 1) << 4))
#define TILE_BYTES 49152

#define GLDS(gsrc, ldst)                                                    \
  __builtin_amdgcn_global_load_lds(                                         \
      (__attribute__((address_space(1))) void*)(void*)(gsrc),               \
      (__attribute__((address_space(3))) void*)(ldst), 16, 0, 0)

#define MFMA8(a, b, c)                                                      \
  __builtin_amdgcn_mfma_scale_f32_16x16x128_f8f6f4(                         \
      (a), (b), (c), 0, 0, 0, 0x7f7f7f7fu, 0, 0x7f7f7f7fu)

__device__ __forceinline__ i32x8 read32(const char* p0, const char* p1) {
  i32x4 lo = *(const i32x4*)p0;
  i32x4 hi = *(const i32x4*)p1;
  return __builtin_shufflevector(lo, hi, 0, 1, 2, 3, 4, 5, 6, 7);
}

#define SB __builtin_amdgcn_sched_barrier(0)
#define LGKM0 asm volatile("s_waitcnt lgkmcnt(0)" ::: "memory")

#define TBODY(CUR, STG, KB)                                                 \
  {                                                                         \
    i32x8 av0, av1, av2, av3, bv0, bv1, bv2, bv3;                           \
    /* ---- phase 0: Q00 ---- */                                            \
    SB;                                                                     \
    av0 = read32((CUR) + arlo[0], (CUR) + arhi[0]);                         \
    av1 = read32((CUR) + arlo[1], (CUR) + arhi[1]);                         \
    bv0 = read32((CUR) + brlo[0], (CUR) + brhi[0]);                         \
    bv1 = read32((CUR) + brlo[1], (CUR) + brhi[1]);                         \
    SB;                                                                     \
    GLDS(agp[0] + (KB), (STG) + aoff[0]);                                   \
    GLDS(agp[1] + (KB), (STG) + aoff[1]);                                   \
    SB;                                                                     \
    __builtin_amdgcn_s_barrier();                                           \
    LGKM0; SB;                                                              \
    __builtin_amdgcn_s_setprio(1);                                          \
    acc[0][0] = MFMA8(av0, bv0, acc[0][0]);                                 \
    acc[0][1] = MFMA8(av0, bv1, acc[0][1]);                                 \
    acc[1][0] = MFMA8(av1, bv0, acc[1][0]);                                 \
    acc[1][1] = MFMA8(av1, bv1, acc[1][1]);                                 \
    __builtin_amdgcn_s_setprio(0);                                          \
    SB;                                                                     \
    /* ---- phase 1: Q10 ---- */                                            \
    av2 = read32((CUR) + arlo[2], (CUR) + arhi[2]);                         \
    av3 = read32((CUR) + arlo[3], (CUR) + arhi[3]);                         \
    SB;                                                                     \
    GLDS(bgp[0] + (KB), (STG) + 16384 + boff[0]);                           \
    GLDS(bgp[1] + (KB), (STG) + 16384 + boff[1]);                           \
    SB;                                                                     \
    __builtin_amdgcn_s_barrier();                                           \
    LGKM0; SB;                                                              \
    __builtin_amdgcn_s_setprio(1);                                          \
    acc[2][0] = MFMA8(av2, bv0, acc[2][0]);                                 \
    acc[2][1] = MFMA8(av2, bv1, acc[2][1]);                                 \
    acc[3][0] = MFMA8(av3, bv0, acc[3][0]);                                 \
    acc[3][1] = MFMA8(av3, bv1, acc[3][1]);                                 \
    __builtin_amdgcn_s_setprio(0);                                          \
    SB;                                                                     \
    /* ---- phase 2: Q01 ---- */                                            \
    bv2 = read32((CUR) + brlo[2], (CUR) + brhi[2]);                         \
    bv3 = read32((CUR) + brlo[3], (CUR) + brhi[3]);                         \
    SB;                                                                     \
    GLDS(bgp[2] + (KB), (STG) + 16384 + boff[2]);                           \
    GLDS(bgp[3] + (KB), (STG) + 16384 + boff[3]);                           \
    SB;                                                                     \
    __builtin_amdgcn_s_barrier();                                           \
    LGKM0; SB;                                                              \
    __builtin_amdgcn_s_setprio(1);                                          \
    acc[0][2] = MFMA8(av0, bv2, acc[0][2]);                                 \
    acc[0][3] = MFMA8(av0, bv3, acc[0][3]);                                 \
    acc[1][2] = MFMA8(av1, bv2, acc[1][2]);                                 \
    acc[1][3] = MFMA8(av1, bv3, acc[1][3]);                                 \
    __builtin_amdgcn_s_setprio(0);                                          \
    SB;                                                                     \
    /* ---- phase 3: Q11 + tile close ---- */                               \
    __builtin_amdgcn_s_barrier();                                           \
    __builtin_amdgcn_s_setprio(1);                                          \
    acc[2][2] = MFMA8(av2, bv2, acc[2][2]);                                 \
    acc[2][3] = MFMA8(av2, bv3, acc[2][3]);                                 \
    acc[3][2] = MFMA8(av3, bv2, acc[3][2]);                                 \
    acc[3][3] = MFMA8(av3, bv3, acc[3][3]);                                 \
    __builtin_amdgcn_s_setprio(0);                                          \
    SB;                                                                     \
    asm volatile("s_waitcnt vmcnt(6)" ::: "memory");                        \
    SB;                                                                     \
    __builtin_amdgcn_s_barrier();                                           \
  }

__global__ __launch_bounds__(512, 1) void gemm_kv_k(
    const unsigned char* __restrict__ A, const unsigned char* __restrict__ B,
    const float* __restrict__ f2, const float* __restrict__ p2,
    __hip_bfloat16* __restrict__ kv) {
  __shared__ __align__(16) char lds[3 * TILE_BYTES];  // 144 KiB
  const int tid = threadIdx.x;
  const int wave = tid >> 6, lane = tid & 63;
  const int q = lane >> 4, l16 = lane & 15;
  const int wr = wave >> 2, wc = wave & 3;

  const int wg = blockIdx.x;
  const int xcd = wg & 7, loc = wg >> 3;
  const int bm = (xcd & 1) * 8 + (loc & 7);
  const int bn = (xcd >> 1) * 4 + (loc >> 3);

  const unsigned char* agp[2];
  const unsigned char* bgp[4];
  int aoff[2], boff[4];
#pragma unroll
  for (int i = 0; i < 2; i++) {
    int phys = (tid + i * 512) * 16;
    aoff[i] = phys;
    int lg = SWZA(phys);
    int kq = lg >> 12, rw = (lg & 4095) >> 5, kl = lg & 31;
    agp[i] = A + (size_t)(bm * 128 + rw) * 4096 + kq * 32 + kl;
  }
#pragma unroll
  for (int i = 0; i < 4; i++) {
    int phys = (tid + i * 512) * 16;
    boff[i] = phys;
    int lg = SWZB(phys);
    int kq = lg >> 13, rw = (lg & 8191) >> 5, kl = lg & 31;
    bgp[i] = B + (size_t)(bn * 256 + rw) * 4096 + kq * 32 + kl;
  }

  int arlo[4], arhi[4], brlo[4], brhi[4];
#pragma unroll
  for (int m = 0; m < 4; m++) {
    int lg = q * 4096 + (wr * 64 + m * 16 + l16) * 32;
    arlo[m] = SWZA(lg);
    arhi[m] = SWZA(lg + 16);
  }
#pragma unroll
  for (int n = 0; n < 4; n++) {
    int lg = q * 8192 + (wc * 64 + n * 16 + l16) * 32;
    brlo[n] = 16384 + SWZB(lg);
    brhi[n] = 16384 + SWZB(lg + 16);
  }

  f32x4 acc[4][4] = {};

  char* b0 = lds;
  char* b1 = lds + TILE_BYTES;
  char* b2 = lds + 2 * TILE_BYTES;

#pragma unroll
  for (int i = 0; i < 2; i++) GLDS(agp[i], b0 + aoff[i]);
#pragma unroll
  for (int i = 0; i < 4; i++) GLDS(bgp[i], b0 + 16384 + boff[i]);
#pragma unroll
  for (int i = 0; i < 2; i++) GLDS(agp[i] + 128, b1 + aoff[i]);
#pragma unroll
  for (int i = 0; i < 4; i++) GLDS(bgp[i] + 128, b1 + 16384 + boff[i]);
  asm volatile("s_waitcnt vmcnt(6)" ::: "memory");
  __builtin_amdgcn_s_barrier();

#pragma unroll 1
  for (int t = 0; t < 32; ++t) {
    const int kb2 = ((t + 2) & 31) * 128;
    TBODY(b0, b2, kb2);
    char* nb0 = b1; char* nb1 = b2; char* nb2 = b0;
    b0 = nb0; b1 = nb1; b2 = nb2;
  }

  asm volatile("s_waitcnt vmcnt(0) lgkmcnt(0)" ::: "memory");

  float p2v[4];
#pragma unroll
  for (int n = 0; n < 4; n++) p2v[n] = p2[bn * 256 + wc * 64 + n * 16 + l16];
#pragma unroll
  for (int m = 0; m < 4; m++) {
#pragma unroll
    for (int j = 0; j < 4; j++) {
      int grow = bm * 128 + wr * 64 + m * 16 + q * 4 + j;
      float f2v = f2[grow];
      __hip_bfloat16* kvp = kv + (size_t)grow * 4096 + bn * 256 + wc * 64 + l16;
#pragma unroll
      for (int n = 0; n < 4; n++) {
        float d2 = fmaxf(f2v + p2v[n] - 2.0f * acc[m][n][j], 0.f);
        kvp[n * 16] = __float2bfloat16(__expf(-GAMMA * d2));
      }
    }
  }
}

// ---------------- Kernel 3: logits = kv @ head_w^T + b; log_softmax ----------------
// 4 rows/block, grid 512. LOW-VGPR structure: class-outer inner loop keeps a
// single float4 w live; part[4][10]=40 + a[4][4]=16 regs. launch_bounds caps 128.
__global__ __launch_bounds__(256, 4) void head_ls_k(
    const __hip_bfloat16* __restrict__ kv, const float* __restrict__ hw,
    const float* __restrict__ hb, float* __restrict__ out) {
  const int bb = blockIdx.x * 4;
  const int tid = threadIdx.x;
  float part[4][10];
#pragma unroll
  for (int r = 0; r < 4; r++)
#pragma unroll
    for (int c = 0; c < 10; c++) part[r][c] = 0.f;

#pragma unroll 1
  for (int k = 0; k < 4; k++) {
    const int idx = tid + k * 256;  // ushort4 chunk index, 0..1023
    float a[4][4];
#pragma unroll
    for (int r = 0; r < 4; r++) {
      ushort4 v = ((const ushort4*)(kv + (size_t)(bb + r) * 4096))[idx];
      a[r][0] = bf2f(v.x); a[r][1] = bf2f(v.y); a[r][2] = bf2f(v.z); a[r][3] = bf2f(v.w);
    }
#pragma unroll
    for (int c = 0; c < 10; c++) {
      float4 w = *(const float4*)(hw + c * 4096 + idx * 4);
#pragma unroll
      for (int r = 0; r < 4; r++)
        part[r][c] += a[r][0] * w.x + a[r][1] * w.y + a[r][2] * w.z + a[r][3] * w.w;
    }
  }

#pragma unroll
  for (int r = 0; r < 4; r++)
#pragma unroll
    for (int c = 0; c < 10; c++)
      for (int off = 32; off > 0; off >>= 1) part[r][c] += __shfl_down(part[r][c], off);

  __shared__ float red[4][4][10];
  if ((tid & 63) == 0) {
#pragma unroll
    for (int r = 0; r < 4; r++)
#pragma unroll
      for (int c = 0; c < 10; c++) red[tid >> 6][r][c] = part[r][c];
  }
  __syncthreads();
  if (tid < 4) {
    const int r = tid;
    float l[10], m = -1e30f;
#pragma unroll
    for (int c = 0; c < 10; c++) {
      l[c] = red[0][r][c] + red[1][r][c] + red[2][r][c] + red[3][r][c] + hb[c];
      m = fmaxf(m, l[c]);
    }
    float s = 0.f;
#pragma unroll
    for (int c = 0; c < 10; c++) s += __expf(l[c] - m);
    float lse = logf(s);
#pragma unroll
    for (int c = 0; c < 10; c++) out[(size_t)(bb + r) * 10 + c] = l[c] - m - lse;
  }
}

extern "C" void kernel_launch(void* const* d_in, const int* in_sizes, int n_in,
                              void* d_out, int out_size, void* d_ws, size_t ws_size,
                              hipStream_t stream) {
  const float* x      = (const float*)d_in[0];
  const float* protos = (const float*)d_in[1];
  const float* conv_w = (const float*)d_in[2];
  const float* conv_b = (const float*)d_in[3];
  const float* head_w = (const float*)d_in[4];
  const float* head_b = (const float*)d_in[5];
  float* out = (float*)d_out;
  char* ws = (char*)d_ws;

  unsigned char* pB8  = (unsigned char*)ws;                      // 4096x4096 fp8 = 16 MB
  unsigned char* fA8  = (unsigned char*)(ws + (16u << 20));      // 2048x4096 fp8 =  8 MB
  __hip_bfloat16* kvb = (__hip_bfloat16*)(ws + (24u << 20));     // 2048x4096 bf16 = 16 MB
  float* f2 = (float*)(ws + (40u << 20));                        // 2048 f32
  float* p2 = (float*)(ws + (40u << 20) + 8192);                 // 4096 f32

  hipLaunchKernelGGL(prep_k, dim3(6144), dim3(256), 0, stream,
                     x, conv_w, conv_b, fA8, f2, protos, pB8, p2);
  hipLaunchKernelGGL(gemm_kv_k, dim3(256), dim3(512), 0, stream, fA8, pB8, f2, p2, kvb);
  hipLaunchKernelGGL(head_ls_k, dim3(512), dim3(256), 0, stream, kvb, head_w, head_b, out);
}